// Round 1
// baseline (3183.661 us; speedup 1.0000x reference)
//
#include <hip/hip_runtime.h>
#include <cstddef>

#define NB 4
#define CC 256
#define LL 4096
#define NG 32
#define CPG 8
#define NH 4
#define DH 64

static constexpr float EPSV  = 1e-5f;
static constexpr float SCALE = 0.125f; // dh^-0.5 = 1/8

// ---------------- GroupNorm ----------------
__global__ __launch_bounds__(256) void gn_kernel(
    const float* __restrict__ x, const float* __restrict__ gamma,
    const float* __restrict__ beta, float* __restrict__ xn) {
  const int blk = blockIdx.x;            // n*NG + g
  const int n = blk >> 5, g = blk & 31;
  const size_t base = ((size_t)n * CC + (size_t)g * CPG) * LL;
  const float* xp = x + base;
  float* op = xn + base;
  const int NE = CPG * LL;               // 32768

  float s = 0.f, ss = 0.f;
  for (int i = threadIdx.x * 4; i < NE; i += 256 * 4) {
    float4 v = *(const float4*)(xp + i);
    s  += v.x + v.y + v.z + v.w;
    ss += v.x * v.x + v.y * v.y + v.z * v.z + v.w * v.w;
  }
  // wave reduce (64 lanes)
  #pragma unroll
  for (int off = 32; off; off >>= 1) {
    s  += __shfl_down(s, off);
    ss += __shfl_down(ss, off);
  }
  __shared__ float r1[4], r2[4], stat[2];
  const int wid = threadIdx.x >> 6, lane = threadIdx.x & 63;
  if (lane == 0) { r1[wid] = s; r2[wid] = ss; }
  __syncthreads();
  if (threadIdx.x == 0) {
    float S = 0.f, SS = 0.f;
    #pragma unroll
    for (int w = 0; w < 4; ++w) { S += r1[w]; SS += r2[w]; }
    float mean = S / NE;
    float var  = SS / NE - mean * mean;
    stat[0] = mean;
    stat[1] = rsqrtf(var + EPSV);
  }
  __syncthreads();
  const float mean = stat[0], rstd = stat[1];
  for (int i = threadIdx.x * 4; i < NE; i += 256 * 4) {
    float4 v = *(const float4*)(xp + i);
    const int c = g * CPG + (i >> 12);   // i/4096
    const float gm = gamma[c], bt = beta[c];
    v.x = (v.x - mean) * rstd * gm + bt;
    v.y = (v.y - mean) * rstd * gm + bt;
    v.z = (v.z - mean) * rstd * gm + bt;
    v.w = (v.w - mean) * rstd * gm + bt;
    *(float4*)(op + i) = v;
  }
}

// ---------------- fused Q/K/V projection ----------------
// grid (LL/256, CC/8, NB); thread owns one l, 8 o's per projection
__global__ __launch_bounds__(256) void qkv_kernel(
    const float* __restrict__ xn, const float* __restrict__ Wq,
    const float* __restrict__ Wk, const float* __restrict__ Wv,
    float* __restrict__ q, float* __restrict__ k, float* __restrict__ v) {
  const int l  = blockIdx.x * 256 + threadIdx.x;
  const int o0 = blockIdx.y * 8;
  const int n  = blockIdx.z;
  const float* xp = xn + (size_t)n * CC * LL + l;
  float aq[8] = {}, ak[8] = {}, av[8] = {};
  for (int c = 0; c < CC; ++c) {
    const float xv = xp[(size_t)c * LL];
    #pragma unroll
    for (int i = 0; i < 8; ++i) {
      aq[i] = fmaf(Wq[(o0 + i) * CC + c], xv, aq[i]);
      ak[i] = fmaf(Wk[(o0 + i) * CC + c], xv, ak[i]);
      av[i] = fmaf(Wv[(o0 + i) * CC + c], xv, av[i]);
    }
  }
  #pragma unroll
  for (int i = 0; i < 8; ++i) {
    const size_t oi = ((size_t)n * CC + o0 + i) * LL + l;
    q[oi] = aq[i]; k[oi] = ak[i]; v[oi] = av[i];
  }
}

// ---------------- block reduce helper (2 values) ----------------
__device__ __forceinline__ void blk_reduce2(float& v0, float& v1, bool do_max,
                                            volatile float* red /*[8]*/) {
  #pragma unroll
  for (int off = 32; off; off >>= 1) {
    float o0 = __shfl_down(v0, off);
    float o1 = __shfl_down(v1, off);
    if (do_max) { v0 = fmaxf(v0, o0); v1 = fmaxf(v1, o1); }
    else        { v0 += o0;           v1 += o1; }
  }
  const int wid = threadIdx.x >> 6, lane = threadIdx.x & 63;
  __syncthreads();
  if (lane == 0) { red[wid] = v0; red[4 + wid] = v1; }
  __syncthreads();
  float r0 = red[0], r1 = red[4];
  #pragma unroll
  for (int w = 1; w < 4; ++w) {
    if (do_max) { r0 = fmaxf(r0, red[w]); r1 = fmaxf(r1, red[4 + w]); }
    else        { r0 += red[w];           r1 += red[4 + w]; }
  }
  v0 = r0; v1 = r1;
}

// ---------------- attention (flash-style, 2 query rows / block) ----------------
// grid (LL/2, NH, NB), block 256
__global__ __launch_bounds__(256) void attn_kernel(
    const float* __restrict__ Q, const float* __restrict__ K,
    const float* __restrict__ V, float* __restrict__ O) {
  __shared__ float p_sh[2][LL];       // 32 KB: score/prob rows
  __shared__ float v_sh[DH][68];      // 17 KB: V tile, padded
  __shared__ float q_sh[2][DH];
  __shared__ float red[8];

  const int t  = threadIdx.x;
  const int l0 = blockIdx.x * 2;
  const int h  = blockIdx.y, n = blockIdx.z;
  const size_t hb = ((size_t)n * CC + (size_t)h * DH) * LL;

  if (t < 128) {
    const int r = t >> 6, d = t & 63;
    q_sh[r][d] = Q[hb + (size_t)d * LL + l0 + r] * SCALE;
  }
  __syncthreads();

  // --- scores: s[r][m] = sum_d q[r][d] * K[d][m], m = jj*1024 + t*4 .. +3
  float4 a0[4], a1[4];
  #pragma unroll
  for (int jj = 0; jj < 4; ++jj) {
    a0[jj] = make_float4(0.f, 0.f, 0.f, 0.f);
    a1[jj] = make_float4(0.f, 0.f, 0.f, 0.f);
  }
  const float* kp = K + hb + t * 4;
  for (int d = 0; d < DH; ++d) {
    const float q0 = q_sh[0][d], q1 = q_sh[1][d];
    const float* kd = kp + (size_t)d * LL;
    #pragma unroll
    for (int jj = 0; jj < 4; ++jj) {
      const float4 kv = *(const float4*)(kd + jj * 1024);
      a0[jj].x = fmaf(q0, kv.x, a0[jj].x);
      a0[jj].y = fmaf(q0, kv.y, a0[jj].y);
      a0[jj].z = fmaf(q0, kv.z, a0[jj].z);
      a0[jj].w = fmaf(q0, kv.w, a0[jj].w);
      a1[jj].x = fmaf(q1, kv.x, a1[jj].x);
      a1[jj].y = fmaf(q1, kv.y, a1[jj].y);
      a1[jj].z = fmaf(q1, kv.z, a1[jj].z);
      a1[jj].w = fmaf(q1, kv.w, a1[jj].w);
    }
  }

  // --- softmax: max
  float m0 = -1e30f, m1 = -1e30f;
  #pragma unroll
  for (int jj = 0; jj < 4; ++jj) {
    m0 = fmaxf(m0, fmaxf(fmaxf(a0[jj].x, a0[jj].y), fmaxf(a0[jj].z, a0[jj].w)));
    m1 = fmaxf(m1, fmaxf(fmaxf(a1[jj].x, a1[jj].y), fmaxf(a1[jj].z, a1[jj].w)));
  }
  blk_reduce2(m0, m1, true, red);

  // --- exp, store p, sum
  float s0 = 0.f, s1 = 0.f;
  #pragma unroll
  for (int jj = 0; jj < 4; ++jj) {
    a0[jj].x = __expf(a0[jj].x - m0); a0[jj].y = __expf(a0[jj].y - m0);
    a0[jj].z = __expf(a0[jj].z - m0); a0[jj].w = __expf(a0[jj].w - m0);
    a1[jj].x = __expf(a1[jj].x - m1); a1[jj].y = __expf(a1[jj].y - m1);
    a1[jj].z = __expf(a1[jj].z - m1); a1[jj].w = __expf(a1[jj].w - m1);
    s0 += a0[jj].x + a0[jj].y + a0[jj].z + a0[jj].w;
    s1 += a1[jj].x + a1[jj].y + a1[jj].z + a1[jj].w;
    *(float4*)&p_sh[0][jj * 1024 + t * 4] = a0[jj];
    *(float4*)&p_sh[1][jj * 1024 + t * 4] = a1[jj];
  }
  blk_reduce2(s0, s1, false, red);   // internal syncs also publish p_sh

  // --- PV: thread owns (r = t>>7, j = (t>>6)&1, d = t&63)
  const int j = (t >> 6) & 1, r = t >> 7, d = t & 63;
  const float* vp = V + hb;
  float acc = 0.f;
  for (int mt = 0; mt < 64; ++mt) {
    __syncthreads();                 // previous tile consumed / p_sh ready
    #pragma unroll
    for (int i = 0; i < 4; ++i) {
      const int u = t + i * 256;
      const int dr = u >> 4, m4 = (u & 15) * 4;
      const float4 vv = *(const float4*)(vp + (size_t)dr * LL + mt * 64 + m4);
      *(float4*)&v_sh[dr][m4] = vv;
    }
    __syncthreads();
    const float* pr = &p_sh[r][mt * 64 + j * 32];
    const float* vr = &v_sh[d][j * 32];
    #pragma unroll
    for (int mi = 0; mi < 32; mi += 4) {
      const float4 pp = *(const float4*)(pr + mi);
      const float4 vv = *(const float4*)(vr + mi);
      acc += pp.x * vv.x + pp.y * vv.y + pp.z * vv.z + pp.w * vv.w;
    }
  }
  __syncthreads();
  float* scratch = &p_sh[0][0];
  scratch[t] = acc;
  __syncthreads();
  if (j == 0) {
    const float den = (r == 0) ? s0 : s1;
    const float val = (acc + scratch[t + 64]) / den;
    O[hb + (size_t)d * LL + l0 + r] = val;
  }
}

// ---------------- output projection + bias ----------------
__global__ __launch_bounds__(256) void proj_kernel(
    const float* __restrict__ A, const float* __restrict__ Wp,
    const float* __restrict__ bp, float* __restrict__ out) {
  const int l  = blockIdx.x * 256 + threadIdx.x;
  const int o0 = blockIdx.y * 8;
  const int n  = blockIdx.z;
  const float* ap = A + (size_t)n * CC * LL + l;
  float acc[8];
  #pragma unroll
  for (int i = 0; i < 8; ++i) acc[i] = bp[o0 + i];
  for (int c = 0; c < CC; ++c) {
    const float xv = ap[(size_t)c * LL];
    #pragma unroll
    for (int i = 0; i < 8; ++i)
      acc[i] = fmaf(Wp[(o0 + i) * CC + c], xv, acc[i]);
  }
  #pragma unroll
  for (int i = 0; i < 8; ++i)
    out[((size_t)n * CC + o0 + i) * LL + l] = acc[i];
}

extern "C" void kernel_launch(void* const* d_in, const int* in_sizes, int n_in,
                              void* d_out, int out_size, void* d_ws, size_t ws_size,
                              hipStream_t stream) {
  const float* x     = (const float*)d_in[0];
  const float* gamma = (const float*)d_in[1];
  const float* beta  = (const float*)d_in[2];
  const float* Wq    = (const float*)d_in[3];
  const float* Wk    = (const float*)d_in[4];
  const float* Wv    = (const float*)d_in[5];
  const float* Wp    = (const float*)d_in[6];
  const float* bp    = (const float*)d_in[7];
  float* out = (float*)d_out;

  const size_t S = (size_t)NB * CC * LL;   // 4,194,304 floats = 16 MB
  float* xn = (float*)d_ws;                // [S]
  float* q  = xn + S;                      // [S]
  float* k  = q + S;                       // [S]
  float* v  = k + S;                       // [S]
  float* ao = xn;                          // reuse xn after qkv consumes it

  gn_kernel  <<<NB * NG,            256, 0, stream>>>(x, gamma, beta, xn);
  qkv_kernel <<<dim3(LL/256, CC/8, NB), 256, 0, stream>>>(xn, Wq, Wk, Wv, q, k, v);
  attn_kernel<<<dim3(LL/2, NH, NB),     256, 0, stream>>>(q, k, v, ao);
  proj_kernel<<<dim3(LL/256, CC/8, NB), 256, 0, stream>>>(ao, Wp, bp, out);
}

// Round 2
// 711.614 us; speedup vs baseline: 4.4739x; 4.4739x over previous
//
#include <hip/hip_runtime.h>
#include <cstddef>
#include <cstdint>

#define NB 4
#define CC 256
#define LL 4096
#define NG 32
#define CPG 8
#define NH 4
#define DH 64

static constexpr float EPSV  = 1e-5f;
static constexpr float SCALE = 0.125f; // dh^-0.5

typedef __attribute__((ext_vector_type(8))) short bf16x8;
typedef __attribute__((ext_vector_type(4))) float f32x4;

__device__ __forceinline__ short f2bf(float f) {
  unsigned u = __float_as_uint(f);
  unsigned r = (u + 0x7fffu + ((u >> 16) & 1u)) >> 16;
  return (short)r;
}
__device__ __forceinline__ float bf2f(short s) {
  return __uint_as_float(((unsigned)(unsigned short)s) << 16);
}
// element offset of 16B chunk (8 bf16) with XOR swizzle: row stride 64 elems
__device__ __forceinline__ int sw(int row, int chunk) {
  return row * 64 + ((chunk ^ (row & 7)) * 8);
}

// ---------------- GroupNorm ----------------
__global__ __launch_bounds__(256) void gn_kernel(
    const float* __restrict__ x, const float* __restrict__ gamma,
    const float* __restrict__ beta, float* __restrict__ xn) {
  const int blk = blockIdx.x;
  const int n = blk >> 5, g = blk & 31;
  const size_t base = ((size_t)n * CC + (size_t)g * CPG) * LL;
  const float* xp = x + base;
  float* op = xn + base;
  const int NE = CPG * LL;

  float s = 0.f, ss = 0.f;
  for (int i = threadIdx.x * 4; i < NE; i += 256 * 4) {
    float4 v = *(const float4*)(xp + i);
    s  += v.x + v.y + v.z + v.w;
    ss += v.x * v.x + v.y * v.y + v.z * v.z + v.w * v.w;
  }
  #pragma unroll
  for (int off = 32; off; off >>= 1) {
    s  += __shfl_down(s, off);
    ss += __shfl_down(ss, off);
  }
  __shared__ float r1[4], r2[4], stat[2];
  const int wid = threadIdx.x >> 6, lane = threadIdx.x & 63;
  if (lane == 0) { r1[wid] = s; r2[wid] = ss; }
  __syncthreads();
  if (threadIdx.x == 0) {
    float S = 0.f, SS = 0.f;
    #pragma unroll
    for (int w = 0; w < 4; ++w) { S += r1[w]; SS += r2[w]; }
    float mean = S / NE;
    float var  = SS / NE - mean * mean;
    stat[0] = mean;
    stat[1] = rsqrtf(var + EPSV);
  }
  __syncthreads();
  const float mean = stat[0], rstd = stat[1];
  for (int i = threadIdx.x * 4; i < NE; i += 256 * 4) {
    float4 v = *(const float4*)(xp + i);
    const int c = g * CPG + (i >> 12);
    const float gm = gamma[c], bt = beta[c];
    v.x = (v.x - mean) * rstd * gm + bt;
    v.y = (v.y - mean) * rstd * gm + bt;
    v.z = (v.z - mean) * rstd * gm + bt;
    v.w = (v.w - mean) * rstd * gm + bt;
    *(float4*)(op + i) = v;
  }
}

// ---------------- fused Q/K/V projection → bf16 MFMA layouts ----------------
// Qt/Kt: [n,h,l,d] (Q pre-scaled by 1/8). V: [n,h,d,l].
__global__ __launch_bounds__(256) void qkv_kernel(
    const float* __restrict__ xn, const float* __restrict__ Wq,
    const float* __restrict__ Wk, const float* __restrict__ Wv,
    short* __restrict__ Qt, short* __restrict__ Kt, short* __restrict__ Vb) {
  const int l  = blockIdx.x * 256 + threadIdx.x;
  const int o0 = blockIdx.y * 8;
  const int n  = blockIdx.z;
  const float* xp = xn + (size_t)n * CC * LL + l;
  float aq[8] = {}, ak[8] = {}, av[8] = {};
  for (int c = 0; c < CC; ++c) {
    const float xv = xp[(size_t)c * LL];
    #pragma unroll
    for (int i = 0; i < 8; ++i) {
      aq[i] = fmaf(Wq[(o0 + i) * CC + c], xv, aq[i]);
      ak[i] = fmaf(Wk[(o0 + i) * CC + c], xv, ak[i]);
      av[i] = fmaf(Wv[(o0 + i) * CC + c], xv, av[i]);
    }
  }
  const int h = o0 >> 6, d0 = o0 & 63;
  const size_t hb = (size_t)(n * NH + h);
  // V: [d][l], coalesced 2B stores across threads
  #pragma unroll
  for (int i = 0; i < 8; ++i)
    Vb[(hb * DH + d0 + i) * LL + l] = f2bf(av[i]);
  // Qt/Kt: [l][d], 16B store per thread
  short tq[8] __attribute__((aligned(16)));
  short tk[8] __attribute__((aligned(16)));
  #pragma unroll
  for (int i = 0; i < 8; ++i) {
    tq[i] = f2bf(aq[i] * SCALE);
    tk[i] = f2bf(ak[i]);
  }
  *(uint4*)(Qt + (hb * LL + l) * DH + d0) = *(const uint4*)tq;
  *(uint4*)(Kt + (hb * LL + l) * DH + d0) = *(const uint4*)tk;
}

// ---------------- MFMA flash attention ----------------
// grid (LL/64, NH, NB), block 256 (4 waves). Wave w owns q rows [l0+16w, +16).
__global__ __launch_bounds__(256) void attn_mfma_kernel(
    const short* __restrict__ Qt, const short* __restrict__ Kt,
    const short* __restrict__ Vb, float* __restrict__ O) {
  __shared__ __align__(16) short k_lds[64 * 64];       // [key][d] swizzled
  __shared__ __align__(16) short v_lds[64 * 64];       // [d][key] swizzled
  __shared__ __align__(16) short p_lds[4][16 * 64];    // per-wave [q][key] swizzled

  const int t = threadIdx.x;
  const int wave = t >> 6, lane = t & 63;
  const int lq = lane & 15, quad = lane >> 4;
  const int l0 = blockIdx.x * 64;
  const int h = blockIdx.y, n = blockIdx.z;
  const size_t hb = (size_t)(n * NH + h) * (size_t)LL * DH;

  // Q A-frags: A[m=lq][k=quad*8+j], kstep 0/1
  const int qrow = l0 + wave * 16 + lq;
  const bf16x8 qa0 = *(const bf16x8*)(Qt + hb + (size_t)qrow * DH + quad * 8);
  const bf16x8 qa1 = *(const bf16x8*)(Qt + hb + (size_t)qrow * DH + 32 + quad * 8);

  f32x4 o0 = {0.f, 0.f, 0.f, 0.f}, o1 = o0, o2 = o0, o3 = o0;
  float m_r[4] = {-1e30f, -1e30f, -1e30f, -1e30f};
  float l_r[4] = {0.f, 0.f, 0.f, 0.f};

  for (int kt = 0; kt < 64; ++kt) {
    const int l0k = kt * 64;
    // ---- stage K/V tiles (8 KB each) ----
    #pragma unroll
    for (int i = 0; i < 2; ++i) {
      const int c = t + i * 256;           // 0..511 16B chunks
      const int row = c >> 3, ch = c & 7;
      *(uint4*)&k_lds[sw(row, ch)] =
          *(const uint4*)(Kt + hb + (size_t)(l0k + row) * DH + ch * 8);
      *(uint4*)&v_lds[sw(row, ch)] =
          *(const uint4*)(Vb + hb + (size_t)row * LL + l0k + ch * 8);
    }
    __syncthreads();

    // ---- S = Q·K^T (16×64 per wave), fp32 accum ----
    f32x4 s[4];
    #pragma unroll
    for (int n0 = 0; n0 < 4; ++n0) {
      const bf16x8 kb0 = *(const bf16x8*)&k_lds[sw(n0 * 16 + lq, quad)];
      const bf16x8 kb1 = *(const bf16x8*)&k_lds[sw(n0 * 16 + lq, 4 + quad)];
      f32x4 z = {0.f, 0.f, 0.f, 0.f};
      z = __builtin_amdgcn_mfma_f32_16x16x32_bf16(qa0, kb0, z, 0, 0, 0);
      s[n0] = __builtin_amdgcn_mfma_f32_16x16x32_bf16(qa1, kb1, z, 0, 0, 0);
    }

    // ---- online softmax (rows quad*4+r, cols n0*16+lq) ----
    float al[4], psum[4];
    #pragma unroll
    for (int r = 0; r < 4; ++r) {
      float v = fmaxf(fmaxf(s[0][r], s[1][r]), fmaxf(s[2][r], s[3][r]));
      v = fmaxf(v, __shfl_xor(v, 1));
      v = fmaxf(v, __shfl_xor(v, 2));
      v = fmaxf(v, __shfl_xor(v, 4));
      v = fmaxf(v, __shfl_xor(v, 8));
      const float mn = fmaxf(m_r[r], v);
      al[r] = __expf(m_r[r] - mn);
      m_r[r] = mn;
    }
    #pragma unroll
    for (int r = 0; r < 4; ++r) {
      const int row = quad * 4 + r;
      float ps = 0.f;
      #pragma unroll
      for (int n0 = 0; n0 < 4; ++n0) {
        const float p = __expf(s[n0][r] - m_r[r]);
        const short pb = f2bf(p);
        ps += bf2f(pb);   // denominator matches bf16 numerator
        p_lds[wave][row * 64 + (((n0 * 2 + (lq >> 3)) ^ (row & 7)) * 8) + (lq & 7)] = pb;
      }
      ps += __shfl_xor(ps, 1);
      ps += __shfl_xor(ps, 2);
      ps += __shfl_xor(ps, 4);
      ps += __shfl_xor(ps, 8);
      l_r[r] = l_r[r] * al[r] + ps;
      o0[r] *= al[r]; o1[r] *= al[r]; o2[r] *= al[r]; o3[r] *= al[r];
    }

    __builtin_amdgcn_s_waitcnt(0);  // drain P writes (wave-private LDS)

    // ---- O += P·V ----
    const bf16x8 pa0 = *(const bf16x8*)&p_lds[wave][sw(lq, quad)];
    const bf16x8 pa1 = *(const bf16x8*)&p_lds[wave][sw(lq, 4 + quad)];
    {
      const bf16x8 vb0 = *(const bf16x8*)&v_lds[sw(lq, quad)];
      const bf16x8 vb1 = *(const bf16x8*)&v_lds[sw(lq, 4 + quad)];
      o0 = __builtin_amdgcn_mfma_f32_16x16x32_bf16(pa0, vb0, o0, 0, 0, 0);
      o0 = __builtin_amdgcn_mfma_f32_16x16x32_bf16(pa1, vb1, o0, 0, 0, 0);
    }
    {
      const bf16x8 vb0 = *(const bf16x8*)&v_lds[sw(16 + lq, quad)];
      const bf16x8 vb1 = *(const bf16x8*)&v_lds[sw(16 + lq, 4 + quad)];
      o1 = __builtin_amdgcn_mfma_f32_16x16x32_bf16(pa0, vb0, o1, 0, 0, 0);
      o1 = __builtin_amdgcn_mfma_f32_16x16x32_bf16(pa1, vb1, o1, 0, 0, 0);
    }
    {
      const bf16x8 vb0 = *(const bf16x8*)&v_lds[sw(32 + lq, quad)];
      const bf16x8 vb1 = *(const bf16x8*)&v_lds[sw(32 + lq, 4 + quad)];
      o2 = __builtin_amdgcn_mfma_f32_16x16x32_bf16(pa0, vb0, o2, 0, 0, 0);
      o2 = __builtin_amdgcn_mfma_f32_16x16x32_bf16(pa1, vb1, o2, 0, 0, 0);
    }
    {
      const bf16x8 vb0 = *(const bf16x8*)&v_lds[sw(48 + lq, quad)];
      const bf16x8 vb1 = *(const bf16x8*)&v_lds[sw(48 + lq, 4 + quad)];
      o3 = __builtin_amdgcn_mfma_f32_16x16x32_bf16(pa0, vb0, o3, 0, 0, 0);
      o3 = __builtin_amdgcn_mfma_f32_16x16x32_bf16(pa1, vb1, o3, 0, 0, 0);
    }
    __syncthreads();
  }

  // ---- epilogue: O /= l, write [c][l] fp32 ----
  float* Op = O + ((size_t)n * CC + h * DH) * LL;
  #pragma unroll
  for (int r = 0; r < 4; ++r) {
    const float inv = 1.0f / l_r[r];
    const int ql = l0 + wave * 16 + quad * 4 + r;
    Op[(size_t)(lq)      * LL + ql] = o0[r] * inv;
    Op[(size_t)(16 + lq) * LL + ql] = o1[r] * inv;
    Op[(size_t)(32 + lq) * LL + ql] = o2[r] * inv;
    Op[(size_t)(48 + lq) * LL + ql] = o3[r] * inv;
  }
}

// ---------------- output projection + bias ----------------
__global__ __launch_bounds__(256) void proj_kernel(
    const float* __restrict__ A, const float* __restrict__ Wp,
    const float* __restrict__ bp, float* __restrict__ out) {
  const int l  = blockIdx.x * 256 + threadIdx.x;
  const int o0 = blockIdx.y * 8;
  const int n  = blockIdx.z;
  const float* ap = A + (size_t)n * CC * LL + l;
  float acc[8];
  #pragma unroll
  for (int i = 0; i < 8; ++i) acc[i] = bp[o0 + i];
  for (int c = 0; c < CC; ++c) {
    const float xv = ap[(size_t)c * LL];
    #pragma unroll
    for (int i = 0; i < 8; ++i)
      acc[i] = fmaf(Wp[(o0 + i) * CC + c], xv, acc[i]);
  }
  #pragma unroll
  for (int i = 0; i < 8; ++i)
    out[((size_t)n * CC + o0 + i) * LL + l] = acc[i];
}

extern "C" void kernel_launch(void* const* d_in, const int* in_sizes, int n_in,
                              void* d_out, int out_size, void* d_ws, size_t ws_size,
                              hipStream_t stream) {
  const float* x     = (const float*)d_in[0];
  const float* gamma = (const float*)d_in[1];
  const float* beta  = (const float*)d_in[2];
  const float* Wq    = (const float*)d_in[3];
  const float* Wk    = (const float*)d_in[4];
  const float* Wv    = (const float*)d_in[5];
  const float* Wp    = (const float*)d_in[6];
  const float* bp    = (const float*)d_in[7];
  float* out = (float*)d_out;

  const size_t S = (size_t)NB * CC * LL;   // 4,194,304 elements
  float* xn = (float*)d_ws;                // 16 MB fp32
  short* Qt = (short*)(xn + S);            // 8 MB bf16 each
  short* Kt = Qt + S;
  short* Vb = Kt + S;
  float* ao = xn;                          // reuse xn after qkv consumes it

  gn_kernel       <<<NB * NG,                 256, 0, stream>>>(x, gamma, beta, xn);
  qkv_kernel      <<<dim3(LL/256, CC/8, NB),  256, 0, stream>>>(xn, Wq, Wk, Wv, Qt, Kt, Vb);
  attn_mfma_kernel<<<dim3(LL/64, NH, NB),     256, 0, stream>>>(Qt, Kt, Vb, ao);
  proj_kernel     <<<dim3(LL/256, CC/8, NB),  256, 0, stream>>>(ao, Wp, bp, out);
}

// Round 3
// 369.150 us; speedup vs baseline: 8.6243x; 1.9277x over previous
//
#include <hip/hip_runtime.h>
#include <cstddef>
#include <cstdint>

#define NB 4
#define CC 256
#define LL 4096
#define NG 32
#define CPG 8
#define NH 4
#define DH 64

static constexpr float EPSV  = 1e-5f;
static constexpr float SCALE = 0.125f; // dh^-0.5

typedef __attribute__((ext_vector_type(8))) short bf16x8;
typedef __attribute__((ext_vector_type(4))) float f32x4;

__device__ __forceinline__ short f2bf(float f) {
  unsigned u = __float_as_uint(f);
  unsigned r = (u + 0x7fffu + ((u >> 16) & 1u)) >> 16;
  return (short)r;
}
__device__ __forceinline__ float bf2f(short s) {
  return __uint_as_float(((unsigned)(unsigned short)s) << 16);
}
__device__ __forceinline__ int sw(int row, int chunk) {
  return row * 64 + ((chunk ^ (row & 7)) * 8);
}

// ---------------- weight fp32 -> bf16 ----------------
__global__ __launch_bounds__(256) void wcvt_kernel(
    const float* __restrict__ Wq, const float* __restrict__ Wk,
    const float* __restrict__ Wv, const float* __restrict__ Wp,
    short* __restrict__ dst) {
  const int which = blockIdx.x >> 5;
  const float* src = (which == 0) ? Wq : (which == 1) ? Wk : (which == 2) ? Wv : Wp;
  const int base = (blockIdx.x & 31) * 2048 + threadIdx.x * 8;
  const float4 v0 = *(const float4*)(src + base);
  const float4 v1 = *(const float4*)(src + base + 4);
  short ob[8] __attribute__((aligned(16)));
  ob[0] = f2bf(v0.x); ob[1] = f2bf(v0.y); ob[2] = f2bf(v0.z); ob[3] = f2bf(v0.w);
  ob[4] = f2bf(v1.x); ob[5] = f2bf(v1.y); ob[6] = f2bf(v1.z); ob[7] = f2bf(v1.w);
  *(uint4*)(dst + which * 65536 + base) = *(const uint4*)ob;
}

// ---------------- GroupNorm -> xnT [n][l][c] bf16 ----------------
__global__ __launch_bounds__(256) void gn_kernel(
    const float* __restrict__ x, const float* __restrict__ gamma,
    const float* __restrict__ beta, short* __restrict__ xnT) {
  const int blk = blockIdx.x;
  const int n = blk >> 5, g = blk & 31;
  const size_t base = ((size_t)n * CC + (size_t)g * CPG) * LL;
  const float* xp = x + base;
  const int NE = CPG * LL;

  float s = 0.f, ss = 0.f;
  for (int i = threadIdx.x * 4; i < NE; i += 256 * 4) {
    float4 v = *(const float4*)(xp + i);
    s  += v.x + v.y + v.z + v.w;
    ss += v.x * v.x + v.y * v.y + v.z * v.z + v.w * v.w;
  }
  #pragma unroll
  for (int off = 32; off; off >>= 1) {
    s  += __shfl_down(s, off);
    ss += __shfl_down(ss, off);
  }
  __shared__ float r1[4], r2[4], stat[2];
  const int wid = threadIdx.x >> 6, lane = threadIdx.x & 63;
  if (lane == 0) { r1[wid] = s; r2[wid] = ss; }
  __syncthreads();
  if (threadIdx.x == 0) {
    float S = 0.f, SS = 0.f;
    #pragma unroll
    for (int w = 0; w < 4; ++w) { S += r1[w]; SS += r2[w]; }
    float mean = S / NE;
    float var  = SS / NE - mean * mean;
    stat[0] = mean;
    stat[1] = rsqrtf(var + EPSV);
  }
  __syncthreads();
  const float mean = stat[0], rstd = stat[1];
  float scl[8], shf[8];
  #pragma unroll
  for (int cc = 0; cc < 8; ++cc) {
    const float gm = gamma[g * CPG + cc];
    scl[cc] = rstd * gm;
    shf[cc] = beta[g * CPG + cc] - mean * rstd * gm;
  }
  // pass 2: per-channel coalesced loads, one 16B store per l
  for (int j = 0; j < 4; ++j) {
    const int l = j * 1024 + threadIdx.x * 4;
    float4 vv[8];
    #pragma unroll
    for (int cc = 0; cc < 8; ++cc)
      vv[cc] = *(const float4*)(xp + (size_t)cc * LL + l);
    short ob[4][8] __attribute__((aligned(16)));
    #pragma unroll
    for (int cc = 0; cc < 8; ++cc) {
      ob[0][cc] = f2bf(vv[cc].x * scl[cc] + shf[cc]);
      ob[1][cc] = f2bf(vv[cc].y * scl[cc] + shf[cc]);
      ob[2][cc] = f2bf(vv[cc].z * scl[cc] + shf[cc]);
      ob[3][cc] = f2bf(vv[cc].w * scl[cc] + shf[cc]);
    }
    short* op = xnT + ((size_t)n * LL + l) * CC + g * CPG;
    #pragma unroll
    for (int ii = 0; ii < 4; ++ii)
      *(uint4*)(op + (size_t)ii * CC) = *(const uint4*)ob[ii];
  }
}

// ---------------- QKV MFMA GEMM ----------------
// grid (256 l-tiles, 4 o-tiles). D[o][l] = sum_c W[o][c] * xnT[l][c].
// No LDS in K-loop: A/B frags direct 16B global (L2-resident).
__global__ __launch_bounds__(256) void qkv_gemm(
    const short* __restrict__ xnT, const short* __restrict__ Wqb,
    const short* __restrict__ Wkb, const short* __restrict__ Wvb,
    short* __restrict__ Qt, short* __restrict__ Kt, short* __restrict__ Vo) {
  const int lt = blockIdx.x, ot = blockIdx.y;
  const int n = lt >> 6, l0 = (lt & 63) << 6;
  const int wave = threadIdx.x >> 6, lane = threadIdx.x & 63;
  const int lq = lane & 15, quad = lane >> 4;

  const int orow = ot * 64 + wave * 16 + lq;
  const short* wqp = Wqb + orow * CC + quad * 8;
  const short* wkp = Wkb + orow * CC + quad * 8;
  const short* wvp = Wvb + orow * CC + quad * 8;
  const short* xp  = xnT + ((size_t)(n * LL + l0) + lq) * CC + quad * 8;

  const f32x4 z = {0.f, 0.f, 0.f, 0.f};
  f32x4 aq[4] = {z, z, z, z}, ak[4] = {z, z, z, z}, av[4] = {z, z, z, z};

  #pragma unroll
  for (int c0 = 0; c0 < 256; c0 += 32) {
    const bf16x8 fq = *(const bf16x8*)(wqp + c0);
    const bf16x8 fk = *(const bf16x8*)(wkp + c0);
    const bf16x8 fv = *(const bf16x8*)(wvp + c0);
    #pragma unroll
    for (int n0 = 0; n0 < 4; ++n0) {
      const bf16x8 fb = *(const bf16x8*)(xp + (size_t)(n0 * 16) * CC + c0);
      aq[n0] = __builtin_amdgcn_mfma_f32_16x16x32_bf16(fq, fb, aq[n0], 0, 0, 0);
      ak[n0] = __builtin_amdgcn_mfma_f32_16x16x32_bf16(fk, fb, ak[n0], 0, 0, 0);
      av[n0] = __builtin_amdgcn_mfma_f32_16x16x32_bf16(fv, fb, av[n0], 0, 0, 0);
    }
  }

  const size_t hb = (size_t)(n * NH + ot);
  // V: [d][l] direct (32B runs per quad)
  #pragma unroll
  for (int n0 = 0; n0 < 4; ++n0)
    #pragma unroll
    for (int r = 0; r < 4; ++r)
      Vo[(hb * DH + wave * 16 + quad * 4 + r) * LL + l0 + n0 * 16 + lq] =
          f2bf(av[n0][r]);
  // Q/K: LDS transpose -> [l][d] 16B coalesced
  __shared__ short qt_lds[64][72], kt_lds[64][72];
  #pragma unroll
  for (int n0 = 0; n0 < 4; ++n0)
    #pragma unroll
    for (int r = 0; r < 4; ++r) {
      qt_lds[n0 * 16 + lq][wave * 16 + quad * 4 + r] = f2bf(aq[n0][r] * SCALE);
      kt_lds[n0 * 16 + lq][wave * 16 + quad * 4 + r] = f2bf(ak[n0][r]);
    }
  __syncthreads();
  #pragma unroll
  for (int i = 0; i < 2; ++i) {
    const int u = threadIdx.x + i * 256;
    const int row = u >> 3, ch = u & 7;
    *(uint4*)(Qt + (hb * LL + l0 + row) * DH + ch * 8) = *(const uint4*)&qt_lds[row][ch * 8];
    *(uint4*)(Kt + (hb * LL + l0 + row) * DH + ch * 8) = *(const uint4*)&kt_lds[row][ch * 8];
  }
}

// ---------------- MFMA flash attention (writes aoT [l][c] bf16) ----------------
__global__ __launch_bounds__(256) void attn_mfma_kernel(
    const short* __restrict__ Qt, const short* __restrict__ Kt,
    const short* __restrict__ Vb, short* __restrict__ aoT) {
  __shared__ __align__(16) short k_lds[64 * 64];
  __shared__ __align__(16) short v_lds[64 * 64];
  __shared__ __align__(16) short p_lds[4][16 * 64];

  const int t = threadIdx.x;
  const int wave = t >> 6, lane = t & 63;
  const int lq = lane & 15, quad = lane >> 4;
  const int l0 = blockIdx.x * 64;
  const int h = blockIdx.y, n = blockIdx.z;
  const size_t hb = (size_t)(n * NH + h) * (size_t)LL * DH;

  const int qrow = l0 + wave * 16 + lq;
  const bf16x8 qa0 = *(const bf16x8*)(Qt + hb + (size_t)qrow * DH + quad * 8);
  const bf16x8 qa1 = *(const bf16x8*)(Qt + hb + (size_t)qrow * DH + 32 + quad * 8);

  f32x4 o0 = {0.f, 0.f, 0.f, 0.f}, o1 = o0, o2 = o0, o3 = o0;
  float m_r[4] = {-1e30f, -1e30f, -1e30f, -1e30f};
  float l_r[4] = {0.f, 0.f, 0.f, 0.f};

  for (int kt = 0; kt < 64; ++kt) {
    const int l0k = kt * 64;
    #pragma unroll
    for (int i = 0; i < 2; ++i) {
      const int c = t + i * 256;
      const int row = c >> 3, ch = c & 7;
      *(uint4*)&k_lds[sw(row, ch)] =
          *(const uint4*)(Kt + hb + (size_t)(l0k + row) * DH + ch * 8);
      *(uint4*)&v_lds[sw(row, ch)] =
          *(const uint4*)(Vb + hb + (size_t)row * LL + l0k + ch * 8);
    }
    __syncthreads();

    f32x4 s[4];
    #pragma unroll
    for (int n0 = 0; n0 < 4; ++n0) {
      const bf16x8 kb0 = *(const bf16x8*)&k_lds[sw(n0 * 16 + lq, quad)];
      const bf16x8 kb1 = *(const bf16x8*)&k_lds[sw(n0 * 16 + lq, 4 + quad)];
      f32x4 zz = {0.f, 0.f, 0.f, 0.f};
      zz = __builtin_amdgcn_mfma_f32_16x16x32_bf16(qa0, kb0, zz, 0, 0, 0);
      s[n0] = __builtin_amdgcn_mfma_f32_16x16x32_bf16(qa1, kb1, zz, 0, 0, 0);
    }

    float al[4];
    #pragma unroll
    for (int r = 0; r < 4; ++r) {
      float v = fmaxf(fmaxf(s[0][r], s[1][r]), fmaxf(s[2][r], s[3][r]));
      v = fmaxf(v, __shfl_xor(v, 1));
      v = fmaxf(v, __shfl_xor(v, 2));
      v = fmaxf(v, __shfl_xor(v, 4));
      v = fmaxf(v, __shfl_xor(v, 8));
      const float mn = fmaxf(m_r[r], v);
      al[r] = __expf(m_r[r] - mn);
      m_r[r] = mn;
    }
    #pragma unroll
    for (int r = 0; r < 4; ++r) {
      const int row = quad * 4 + r;
      float ps = 0.f;
      #pragma unroll
      for (int n0 = 0; n0 < 4; ++n0) {
        const float p = __expf(s[n0][r] - m_r[r]);
        const short pb = f2bf(p);
        ps += bf2f(pb);
        p_lds[wave][row * 64 + (((n0 * 2 + (lq >> 3)) ^ (row & 7)) * 8) + (lq & 7)] = pb;
      }
      ps += __shfl_xor(ps, 1);
      ps += __shfl_xor(ps, 2);
      ps += __shfl_xor(ps, 4);
      ps += __shfl_xor(ps, 8);
      l_r[r] = l_r[r] * al[r] + ps;
      o0[r] *= al[r]; o1[r] *= al[r]; o2[r] *= al[r]; o3[r] *= al[r];
    }

    __builtin_amdgcn_s_waitcnt(0);

    const bf16x8 pa0 = *(const bf16x8*)&p_lds[wave][sw(lq, quad)];
    const bf16x8 pa1 = *(const bf16x8*)&p_lds[wave][sw(lq, 4 + quad)];
    {
      const bf16x8 vb0 = *(const bf16x8*)&v_lds[sw(lq, quad)];
      const bf16x8 vb1 = *(const bf16x8*)&v_lds[sw(lq, 4 + quad)];
      o0 = __builtin_amdgcn_mfma_f32_16x16x32_bf16(pa0, vb0, o0, 0, 0, 0);
      o0 = __builtin_amdgcn_mfma_f32_16x16x32_bf16(pa1, vb1, o0, 0, 0, 0);
    }
    {
      const bf16x8 vb0 = *(const bf16x8*)&v_lds[sw(16 + lq, quad)];
      const bf16x8 vb1 = *(const bf16x8*)&v_lds[sw(16 + lq, 4 + quad)];
      o1 = __builtin_amdgcn_mfma_f32_16x16x32_bf16(pa0, vb0, o1, 0, 0, 0);
      o1 = __builtin_amdgcn_mfma_f32_16x16x32_bf16(pa1, vb1, o1, 0, 0, 0);
    }
    {
      const bf16x8 vb0 = *(const bf16x8*)&v_lds[sw(32 + lq, quad)];
      const bf16x8 vb1 = *(const bf16x8*)&v_lds[sw(32 + lq, 4 + quad)];
      o2 = __builtin_amdgcn_mfma_f32_16x16x32_bf16(pa0, vb0, o2, 0, 0, 0);
      o2 = __builtin_amdgcn_mfma_f32_16x16x32_bf16(pa1, vb1, o2, 0, 0, 0);
    }
    {
      const bf16x8 vb0 = *(const bf16x8*)&v_lds[sw(48 + lq, quad)];
      const bf16x8 vb1 = *(const bf16x8*)&v_lds[sw(48 + lq, 4 + quad)];
      o3 = __builtin_amdgcn_mfma_f32_16x16x32_bf16(pa0, vb0, o3, 0, 0, 0);
      o3 = __builtin_amdgcn_mfma_f32_16x16x32_bf16(pa1, vb1, o3, 0, 0, 0);
    }
    __syncthreads();
  }

  // epilogue: write bf16 [l][c]
  #pragma unroll
  for (int r = 0; r < 4; ++r) {
    const float inv = 1.0f / l_r[r];
    const int ql = l0 + wave * 16 + quad * 4 + r;
    const size_t rowb = ((size_t)n * LL + ql) * CC + h * DH;
    aoT[rowb + lq]      = f2bf(o0[r] * inv);
    aoT[rowb + 16 + lq] = f2bf(o1[r] * inv);
    aoT[rowb + 32 + lq] = f2bf(o2[r] * inv);
    aoT[rowb + 48 + lq] = f2bf(o3[r] * inv);
  }
}

// ---------------- output projection MFMA GEMM ----------------
__global__ __launch_bounds__(256) void proj_gemm(
    const short* __restrict__ aoT, const short* __restrict__ Wpb,
    const float* __restrict__ bp, float* __restrict__ out) {
  const int lt = blockIdx.x, ot = blockIdx.y;
  const int n = lt >> 6, l0 = (lt & 63) << 6;
  const int wave = threadIdx.x >> 6, lane = threadIdx.x & 63;
  const int lq = lane & 15, quad = lane >> 4;

  const short* wpp = Wpb + (ot * 64 + wave * 16 + lq) * CC + quad * 8;
  const short* ap  = aoT + ((size_t)(n * LL + l0) + lq) * CC + quad * 8;

  const f32x4 z = {0.f, 0.f, 0.f, 0.f};
  f32x4 acc[4] = {z, z, z, z};
  #pragma unroll
  for (int c0 = 0; c0 < 256; c0 += 32) {
    const bf16x8 fa = *(const bf16x8*)(wpp + c0);
    #pragma unroll
    for (int n0 = 0; n0 < 4; ++n0) {
      const bf16x8 fb = *(const bf16x8*)(ap + (size_t)(n0 * 16) * CC + c0);
      acc[n0] = __builtin_amdgcn_mfma_f32_16x16x32_bf16(fa, fb, acc[n0], 0, 0, 0);
    }
  }
  #pragma unroll
  for (int r = 0; r < 4; ++r) {
    const int o = ot * 64 + wave * 16 + quad * 4 + r;
    const float bias = bp[o];
    #pragma unroll
    for (int n0 = 0; n0 < 4; ++n0)
      out[((size_t)n * CC + o) * LL + l0 + n0 * 16 + lq] = acc[n0][r] + bias;
  }
}

extern "C" void kernel_launch(void* const* d_in, const int* in_sizes, int n_in,
                              void* d_out, int out_size, void* d_ws, size_t ws_size,
                              hipStream_t stream) {
  const float* x     = (const float*)d_in[0];
  const float* gamma = (const float*)d_in[1];
  const float* beta  = (const float*)d_in[2];
  const float* Wq    = (const float*)d_in[3];
  const float* Wk    = (const float*)d_in[4];
  const float* Wv    = (const float*)d_in[5];
  const float* Wp    = (const float*)d_in[6];
  const float* bp    = (const float*)d_in[7];
  float* out = (float*)d_out;

  const size_t S = (size_t)NB * CC * LL;  // 4,194,304
  short* xnT = (short*)d_ws;              // bf16 [n][l][c]
  short* Qt  = xnT + S;                   // bf16 [n,h][l][d]
  short* Kt  = Qt + S;
  short* Vo  = Kt + S;                    // bf16 [n,h][d][l]
  short* aoT = Vo + S;                    // bf16 [n][l][c]
  short* Wb  = aoT + S;                   // 4 x 65536 bf16

  gn_kernel  <<<NB * NG,              256, 0, stream>>>(x, gamma, beta, xnT);
  wcvt_kernel<<<128,                  256, 0, stream>>>(Wq, Wk, Wv, Wp, Wb);
  qkv_gemm   <<<dim3(256, 4),         256, 0, stream>>>(xnT, Wb, Wb + 65536, Wb + 131072, Qt, Kt, Vo);
  attn_mfma_kernel<<<dim3(LL/64, NH, NB), 256, 0, stream>>>(Qt, Kt, Vo, aoT);
  proj_gemm  <<<dim3(256, 4),         256, 0, stream>>>(aoT, Wb + 196608, bp, out);
}